// Round 8
// baseline (121.042 us; speedup 1.0000x reference)
//
#include <hip/hip_runtime.h>
#include <math.h>

#define BATCHN 4096
#define DMODEL 1024
#define NT 64
#define RANK 8
#define K2 512   // NT*RANK

typedef __attribute__((ext_vector_type(8))) short bf16x8;
typedef __attribute__((ext_vector_type(4))) float f32x4;

__device__ __forceinline__ short f2bf_hu(float f) {   // round half-up (1 add)
    unsigned u = __builtin_bit_cast(unsigned, f);
    return (short)((u + 0x8000u) >> 16);
}

__device__ __forceinline__ short f2bf(float f) {      // RNE
    unsigned u = __builtin_bit_cast(unsigned, f);
    u += 0x7fffu + ((u >> 16) & 1u);
    return (short)(u >> 16);
}

__device__ __forceinline__ bf16x8 cvt8(const float* __restrict__ p) {
    float4 v0 = *(const float4*)p;
    float4 v1 = *(const float4*)(p + 4);
    bf16x8 o;
    o[0] = f2bf_hu(v0.x); o[1] = f2bf_hu(v0.y); o[2] = f2bf_hu(v0.z); o[3] = f2bf_hu(v0.w);
    o[4] = f2bf_hu(v1.x); o[5] = f2bf_hu(v1.y); o[6] = f2bf_hu(v1.z); o[7] = f2bf_hu(v1.w);
    return o;
}

// K1: grid 640 x 256. Blocks 0..575: C = x @ [enc;V]^T tiles (BM=64,BN=64,BK=128),
// fp32 inputs staged to bf16 LDS in-register. bn==0 -> gate, bn>=1 -> vx (bf16).
// Blocks 576..639: Frobenius norms (one n each).
__global__ __launch_bounds__(256) void gatevx_norms_kernel(
    const float* __restrict__ x, const float* __restrict__ V,
    const float* __restrict__ U, const float* __restrict__ enc,
    const float* __restrict__ bias,
    float* __restrict__ gate, float* __restrict__ fro,
    unsigned short* __restrict__ vx)
{
    __shared__ unsigned short As[64 * 128];   // 16 KB
    __shared__ unsigned short Bs[64 * 128];   // 16 KB
    __shared__ float red[8];
    const int bid = blockIdx.x, t = threadIdx.x;
    const int wave = t >> 6, lane = t & 63;
    const int wm = wave & 1, wn = wave >> 1;
    const int l15 = lane & 15, lq = lane >> 4;

    if (bid < 576) {
        const int bn = bid % 9, bm = bid / 9;
        const float* Brow = (bn == 0) ? enc : (V + (size_t)(bn - 1) * 64 * DMODEL);
        f32x4 acc[2][2] = {};
        for (int k0 = 0; k0 < DMODEL; k0 += 128) {
            #pragma unroll
            for (int c = 0; c < 4; ++c) {
                const int row = wave * 16 + c * 4 + lq;
                const int g = l15 ^ (row & 15);
                bf16x8 oa = cvt8(x + (size_t)(bm * 64 + row) * DMODEL + k0 + g * 8);
                *(bf16x8*)&As[row * 128 + l15 * 8] = oa;
                bf16x8 ob = cvt8(Brow + (size_t)row * DMODEL + k0 + g * 8);
                *(bf16x8*)&Bs[row * 128 + l15 * 8] = ob;
            }
            __syncthreads();
            #pragma unroll
            for (int s = 0; s < 4; ++s) {
                const int kc = s * 4 + lq;
                bf16x8 af[2], bfr[2];
                #pragma unroll
                for (int i = 0; i < 2; ++i) {
                    const int m = wm * 32 + i * 16 + l15;
                    af[i] = *(const bf16x8*)&As[m * 128 + ((kc ^ (m & 15)) * 8)];
                }
                #pragma unroll
                for (int j = 0; j < 2; ++j) {
                    const int n = wn * 32 + j * 16 + l15;
                    bfr[j] = *(const bf16x8*)&Bs[n * 128 + ((kc ^ (n & 15)) * 8)];
                }
                #pragma unroll
                for (int i = 0; i < 2; ++i)
                    #pragma unroll
                    for (int j = 0; j < 2; ++j)
                        acc[i][j] = __builtin_amdgcn_mfma_f32_16x16x32_bf16(
                            af[i], bfr[j], acc[i][j], 0, 0, 0);
            }
            __syncthreads();
        }
        #pragma unroll
        for (int i = 0; i < 2; ++i) {
            const int rowb = bm * 64 + wm * 32 + i * 16 + lq * 4;
            #pragma unroll
            for (int j = 0; j < 2; ++j) {
                const int col = wn * 32 + j * 16 + l15;
                #pragma unroll
                for (int r = 0; r < 4; ++r) {
                    const int row = rowb + r;
                    const float v = acc[i][j][r];
                    if (bn == 0) {
                        const float p = v - bias[col];
                        gate[(size_t)row * NT + col] = p > 0.f ? p : 0.f;
                    } else {
                        vx[(size_t)row * K2 + (bn - 1) * 64 + col] = (unsigned short)f2bf(v);
                    }
                }
            }
        }
    } else {
        const int n = bid - 576;
        const float* Up = U + (size_t)n * (DMODEL * RANK);
        const float* Vp = V + (size_t)n * (DMODEL * RANK);
        float su = 0.f, sv = 0.f;
        for (int i = t * 4; i < DMODEL * RANK; i += 1024) {
            float4 a = *(const float4*)(Up + i);
            su += a.x * a.x + a.y * a.y + a.z * a.z + a.w * a.w;
            float4 b = *(const float4*)(Vp + i);
            sv += b.x * b.x + b.y * b.y + b.z * b.z + b.w * b.w;
        }
        #pragma unroll
        for (int off = 32; off; off >>= 1) {
            su += __shfl_down(su, off);
            sv += __shfl_down(sv, off);
        }
        if ((t & 63) == 0) { red[wave * 2] = su; red[wave * 2 + 1] = sv; }
        __syncthreads();
        if (t == 0) {
            float tu = red[0] + red[2] + red[4] + red[6];
            float tv = red[1] + red[3] + red[5] + red[7];
            fro[n] = sqrtf(tu) * sqrtf(tv) / sqrtf((float)(DMODEL * RANK));
        }
    }
}

// K2: out = (gate ⊙ vx) @ U^T, U fp32 native [n][d][r] staged to bf16.
// grid (16,64) = 1024 blocks, BM=64 BN=64 BK=128, 32 KB LDS -> 4 blocks/CU.
__global__ __launch_bounds__(256) void out_kernel(
    const unsigned short* __restrict__ vx, const float* __restrict__ gate,
    const float* __restrict__ U, float* __restrict__ out)
{
    __shared__ unsigned short As[64 * 128];      // 16 KB [m][chunk]
    __shared__ unsigned short Bs[16 * 64 * 8];   // 16 KB [kc(=n_local)][d][r]
    const int t = threadIdx.x;
    const int wave = t >> 6, lane = t & 63;
    const int bm = blockIdx.y, bn = blockIdx.x;
    const int wm = wave & 1, wn = wave >> 1;
    const int l15 = lane & 15, lq = lane >> 4;

    f32x4 acc[2][2] = {};

    for (int k0 = 0; k0 < K2; k0 += 128) {
        const int nb = k0 >> 3;
        // A: gated vx (bf16 in, fp32 gate, bf16 out), swizzled chunks
        #pragma unroll
        for (int i = 0; i < 4; ++i) {
            const int row = wave * 16 + i * 4 + lq;
            const int grow = bm * 64 + row;
            const int g = l15 ^ (row & 15);
            bf16x8 v = *(const bf16x8*)(vx + (size_t)grow * K2 + k0 + g * 8);
            const float gs = gate[(size_t)grow * NT + nb + g];
            bf16x8 o;
            #pragma unroll
            for (int e = 0; e < 8; ++e) {
                const float f = __builtin_bit_cast(float,
                    ((unsigned)(unsigned short)v[e]) << 16);
                o[e] = (short)(__builtin_bit_cast(unsigned, f * gs) >> 16);  // trunc
            }
            *(bf16x8*)&As[row * 128 + l15 * 8] = o;
        }
        // B: U fp32 native [n][d][r] -> bf16; lane covers 8 r's = 32 B contiguous
        #pragma unroll
        for (int c = 0; c < 4; ++c) {
            const int kc = c * 4 + wave;
            bf16x8 o = cvt8(U + (size_t)(nb + kc) * (DMODEL * RANK)
                              + (size_t)(bn * 64 + lane) * RANK);
            *(bf16x8*)&Bs[kc * 512 + lane * 8] = o;
        }
        __syncthreads();
        #pragma unroll
        for (int s = 0; s < 4; ++s) {
            const int kc = s * 4 + lq;
            bf16x8 af[2], bfr[2];
            #pragma unroll
            for (int i = 0; i < 2; ++i) {
                const int m = wm * 32 + i * 16 + l15;
                af[i] = *(const bf16x8*)&As[m * 128 + ((kc ^ (m & 15)) * 8)];
            }
            #pragma unroll
            for (int j = 0; j < 2; ++j) {
                const int n = wn * 32 + j * 16 + l15;
                bfr[j] = *(const bf16x8*)&Bs[kc * 512 + n * 8];
            }
            #pragma unroll
            for (int i = 0; i < 2; ++i)
                #pragma unroll
                for (int j = 0; j < 2; ++j)
                    acc[i][j] = __builtin_amdgcn_mfma_f32_16x16x32_bf16(
                        af[i], bfr[j], acc[i][j], 0, 0, 0);
        }
        __syncthreads();
    }

    #pragma unroll
    for (int i = 0; i < 2; ++i) {
        const int rowb = bm * 64 + wm * 32 + i * 16 + lq * 4;
        #pragma unroll
        for (int j = 0; j < 2; ++j) {
            const int col = bn * 64 + wn * 32 + j * 16 + l15;
            #pragma unroll
            for (int r = 0; r < 4; ++r)
                out[(size_t)(rowb + r) * DMODEL + col] = acc[i][j][r];
        }
    }
}

extern "C" void kernel_launch(void* const* d_in, const int* in_sizes, int n_in,
                              void* d_out, int out_size, void* d_ws, size_t ws_size,
                              hipStream_t stream) {
    const float* x    = (const float*)d_in[0];
    const float* V    = (const float*)d_in[1];
    const float* U    = (const float*)d_in[2];
    const float* enc  = (const float*)d_in[3];
    const float* bias = (const float*)d_in[4];

    float* out  = (float*)d_out;                       // [4096,1024]
    float* gate = out + (size_t)BATCHN * DMODEL;       // [4096,64] fp32
    float* fro  = gate + (size_t)BATCHN * NT;          // [64]
    unsigned short* vx = (unsigned short*)d_ws;        // [4096,512] bf16 = 4 MB

    gatevx_norms_kernel<<<640, 256, 0, stream>>>(x, V, U, enc, bias, gate, fro, vx);
    out_kernel<<<dim3(16, 64), 256, 0, stream>>>(vx, gate, U, out);
}